// Round 7
// baseline (324.197 us; speedup 1.0000x reference)
//
#include <hip/hip_runtime.h>
#include <hip/hip_bf16.h>
#include <math.h>

#define B_ 32
#define N_ 576
#define C_ 1024
#define INNER_ 256
#define H_ 4
#define HD_ 64
#define M_ (B_*N_)           // 18432
#define ALPHA_ 5.0f
#define EPS_ 1e-5f

typedef __attribute__((ext_vector_type(8))) short bf16x8;
typedef __attribute__((ext_vector_type(4))) float f32x4;
typedef __attribute__((ext_vector_type(4))) unsigned int u32x4;
typedef unsigned short u16;

__device__ inline u16 bfbits(float x) {
    union { __hip_bfloat16 h; u16 u; } c; c.h = __float2bfloat16(x); return c.u;
}
__device__ inline unsigned pack2bf(float a, float b) {
    return (unsigned)bfbits(a) | ((unsigned)bfbits(b) << 16);
}

// Async global->LDS, 16B per lane. LDS dest must be wave-uniform base + lane*16.
__device__ __forceinline__ void gld16(void* lds, const void* g) {
    __builtin_amdgcn_global_load_lds(
        (const __attribute__((address_space(1))) unsigned int*)g,
        (__attribute__((address_space(3))) unsigned int*)lds, 16, 0, 0);
}

// XCD row-clustering swizzle: all GX column-blocks of a row-band map to one
// XCD so the A-tile stays in that XCD's L2.
template<int GX, int GY>
__device__ inline void xcd_remap(int& col, int& row) {
    int f = blockIdx.y * GX + blockIdx.x;
    int xcd = f & 7;
    int slot = f >> 3;
    col = slot % GX;
    row = xcd * (GY >> 3) + slot / GX;
}

// ---------------------------------------------------------------------------
// Fused LayerNorm for both tensors in one launch; query pass (blockIdx.y==0)
// also emits the raw input as bf16 (Xq) for the gate GEMM.
// ---------------------------------------------------------------------------
__global__ void ln_fused2_kernel(const float* __restrict__ Xq, const float* __restrict__ Xs,
                                 const float* __restrict__ wq, const float* __restrict__ bq,
                                 const float* __restrict__ ws, const float* __restrict__ bs,
                                 u16* __restrict__ outq, u16* __restrict__ outs,
                                 u16* __restrict__ outraw) {
    const float* X; const float* w; const float* b; u16* o;
    bool raw = (blockIdx.y == 0);
    if (raw) { X = Xq; w = wq; b = bq; o = outq; }
    else     { X = Xs; w = ws; b = bs; o = outs; }
    int row = blockIdx.x * 4 + (threadIdx.x >> 6);
    int lane = threadIdx.x & 63;
    const float* xp = X + (size_t)row * C_;
    float4 v[4];
    #pragma unroll
    for (int j = 0; j < 4; ++j) v[j] = *(const float4*)(xp + lane*4 + j*256);
    float s = 0.f, s2 = 0.f;
    #pragma unroll
    for (int j = 0; j < 4; ++j) {
        s  += v[j].x + v[j].y + v[j].z + v[j].w;
        s2 += v[j].x*v[j].x + v[j].y*v[j].y + v[j].z*v[j].z + v[j].w*v[j].w;
    }
    #pragma unroll
    for (int m = 32; m; m >>= 1) {
        s  += __shfl_xor(s,  m, 64);
        s2 += __shfl_xor(s2, m, 64);
    }
    float mean = s * (1.f/C_);
    float rs = rsqrtf(s2 * (1.f/C_) - mean*mean + EPS_);
    #pragma unroll
    for (int j = 0; j < 4; ++j) {
        int k = lane*4 + j*256;
        float4 wv = *(const float4*)(w + k);
        float4 bv = *(const float4*)(b + k);
        ushort4 ov;
        ov.x = bfbits((v[j].x - mean)*rs*wv.x + bv.x);
        ov.y = bfbits((v[j].y - mean)*rs*wv.y + bv.y);
        ov.z = bfbits((v[j].z - mean)*rs*wv.z + bv.z);
        ov.w = bfbits((v[j].w - mean)*rs*wv.w + bv.w);
        *(ushort4*)(o + (size_t)row*C_ + k) = ov;
        if (raw) {
            ushort4 r4;
            r4.x = bfbits(v[j].x); r4.y = bfbits(v[j].y);
            r4.z = bfbits(v[j].z); r4.w = bfbits(v[j].w);
            *(ushort4*)(outraw + (size_t)row*C_ + k) = r4;
        }
    }
}

// ---------------------------------------------------------------------------
// All weight conversions in one kernel + combined K/V bias.
// ---------------------------------------------------------------------------
__global__ void cvt_weights_kernel(const float* __restrict__ Wq, const float* __restrict__ Wk,
                                   const float* __restrict__ Wv, const float* __restrict__ Wo,
                                   const float* __restrict__ Wg,
                                   const float* __restrict__ bk, const float* __restrict__ bv,
                                   u16* __restrict__ Wq_b, u16* __restrict__ Wkv_b,
                                   u16* __restrict__ Wo_b, u16* __restrict__ Wg_b,
                                   float* __restrict__ bkv) {
    if (blockIdx.x == 0 && threadIdx.x < 128) {
        float4 t = (threadIdx.x < 64) ? ((const float4*)bk)[threadIdx.x]
                                      : ((const float4*)bv)[threadIdx.x - 64];
        ((float4*)bkv)[threadIdx.x] = t;
    }
    int g = blockIdx.x * 256 + threadIdx.x;
    const float* src; u16* dst; size_t off;
    if (g < 32768)       { src = Wq; dst = Wq_b;          off = (size_t)g*8; }
    else if (g < 65536)  { src = Wk; dst = Wkv_b;         off = (size_t)(g-32768)*8; }
    else if (g < 98304)  { src = Wv; dst = Wkv_b + 262144; off = (size_t)(g-65536)*8; }
    else if (g < 131072) { src = Wo; dst = Wo_b;          off = (size_t)(g-98304)*8; }
    else                 { src = Wg; dst = Wg_b;          off = (size_t)(g-131072)*8; }
    float4 a0 = *(const float4*)(src + off);
    float4 a1 = *(const float4*)(src + off + 4);
    union { u16 s[8]; u32x4 v; } o;
    o.s[0] = bfbits(a0.x); o.s[1] = bfbits(a0.y); o.s[2] = bfbits(a0.z); o.s[3] = bfbits(a0.w);
    o.s[4] = bfbits(a1.x); o.s[5] = bfbits(a1.y); o.s[6] = bfbits(a1.z); o.s[7] = bfbits(a1.w);
    *(u32x4*)(dst + off) = o.v;
}

// ---------------------------------------------------------------------------
// GEMM inner: 128x128 tile, BK=64, 4 waves, 4x4 frags of 16x16x32 bf16.
// Staging via global_load_lds width=16 into LINEAR [128][64] LDS (m97 style).
// ---------------------------------------------------------------------------
template<int KDIM>
__device__ __forceinline__ void gemm_accum_async(const u16* __restrict__ A,
                                                 const u16* __restrict__ Bw,
                                                 int row0, int col0, int tid, int lane,
                                                 int wm, int wn,
                                                 u16 (&Asm)[128][64], u16 (&Bsm)[128][64],
                                                 f32x4 (&acc)[4][4]) {
    int rb = tid >> 3, cg = (tid & 7) * 8;
    for (int k0 = 0; k0 < KDIM; k0 += 64) {
        #pragma unroll
        for (int p = 0; p < 4; ++p) {
            int rr = p*32 + rb;
            gld16(&Asm[0][0] + ((size_t)(p*256 + tid))*8,
                  A + (size_t)(row0 + rr)*KDIM + k0 + cg);
            gld16(&Bsm[0][0] + ((size_t)(p*256 + tid))*8,
                  Bw + (size_t)(col0 + rr)*KDIM + k0 + cg);
        }
        __syncthreads();
        #pragma unroll
        for (int ks = 0; ks < 64; ks += 32) {
            bf16x8 af[4], bfr[4];
            #pragma unroll
            for (int i = 0; i < 4; ++i)
                af[i] = *(const bf16x8*)&Asm[wm + i*16 + (lane & 15)][ks + (lane >> 4)*8];
            #pragma unroll
            for (int j = 0; j < 4; ++j)
                bfr[j] = *(const bf16x8*)&Bsm[wn + j*16 + (lane & 15)][ks + (lane >> 4)*8];
            #pragma unroll
            for (int i = 0; i < 4; ++i)
                #pragma unroll
                for (int j = 0; j < 4; ++j)
                    acc[i][j] = __builtin_amdgcn_mfma_f32_16x16x32_bf16(
                        af[i], bfr[j], acc[i][j], 0, 0, 0);
        }
        __syncthreads();
    }
}

// ---------------------------------------------------------------------------
// Q + KV projections in one launch. grid (6,144) swizzled: col-blocks 0-1 = Q,
// 2-5 = KV.
// ---------------------------------------------------------------------------
__global__ __launch_bounds__(256, 4)
void qkv_gemm_kernel(const u16* __restrict__ Aq, const u16* __restrict__ As,
                     const u16* __restrict__ Wq_b, const u16* __restrict__ Wkv_b,
                     const float* __restrict__ bq, const float* __restrict__ bkv,
                     u16* __restrict__ Qbf, u16* __restrict__ KVbf) {
    __shared__ u16 Asm[128][64];
    __shared__ u16 Bsm[128][64];
    int tid = threadIdx.x;
    int lane = tid & 63, wid = tid >> 6;
    int wm = (wid >> 1) * 64, wn = (wid & 1) * 64;
    int bc, br;
    xcd_remap<6, 144>(bc, br);
    int row0 = br * 128;
    bool isQ = (bc < 2);
    int col0 = (isQ ? bc : bc - 2) * 128;
    const u16* A  = isQ ? Aq   : As;
    const u16* Bw = isQ ? Wq_b : Wkv_b;
    const float* bias = isQ ? bq : bkv;
    u16* Out = isQ ? Qbf : KVbf;
    const int NOUT = isQ ? INNER_ : 2*INNER_;
    f32x4 acc[4][4] = {};
    gemm_accum_async<C_>(A, Bw, row0, col0, tid, lane, wm, wn, Asm, Bsm, acc);
    #pragma unroll
    for (int i = 0; i < 4; ++i) {
        #pragma unroll
        for (int j = 0; j < 4; ++j) {
            int col = col0 + wn + j*16 + (lane & 15);
            float bb = bias[col];
            #pragma unroll
            for (int r = 0; r < 4; ++r) {
                int row = row0 + wm + i*16 + (lane >> 4)*4 + r;
                Out[(size_t)row * NOUT + col] = bfbits(acc[i][j][r] + bb);
            }
        }
    }
}

// ---------------------------------------------------------------------------
// Fused gate + output projection + residual:
// out = query + sigmoid(Xq@Wg^T + bg) * (ctx@Wo^T + bo), f32 out.
// ---------------------------------------------------------------------------
__global__ __launch_bounds__(256, 3)
void final_fused_kernel(const float* __restrict__ query, const u16* __restrict__ Xq,
                        const u16* __restrict__ Wg_b, const float* __restrict__ bg,
                        const u16* __restrict__ ctxb, const u16* __restrict__ Wo_b,
                        const float* __restrict__ bo, float* __restrict__ out) {
    __shared__ u16 Asm[128][64];
    __shared__ u16 Bsm[128][64];
    int tid = threadIdx.x;
    int lane = tid & 63, wid = tid >> 6;
    int wm = (wid >> 1) * 64, wn = (wid & 1) * 64;
    int bc, br;
    xcd_remap<8, 144>(bc, br);
    int row0 = br * 128, col0 = bc * 128;
    f32x4 acc_o[4][4] = {};
    f32x4 acc_g[4][4] = {};
    gemm_accum_async<INNER_>(ctxb, Wo_b, row0, col0, tid, lane, wm, wn, Asm, Bsm, acc_o);
    gemm_accum_async<C_>(Xq, Wg_b, row0, col0, tid, lane, wm, wn, Asm, Bsm, acc_g);
    #pragma unroll
    for (int i = 0; i < 4; ++i) {
        #pragma unroll
        for (int j = 0; j < 4; ++j) {
            int col = col0 + wn + j*16 + (lane & 15);
            float bgv = bg[col], bov = bo[col];
            #pragma unroll
            for (int r = 0; r < 4; ++r) {
                int row = row0 + wm + i*16 + (lane >> 4)*4 + r;
                size_t idx = (size_t)row * C_ + col;
                float g = 1.f / (1.f + expf(-(acc_g[i][j][r] + bgv)));
                __builtin_nontemporal_store(query[idx] + g * (acc_o[i][j][r] + bov), &out[idx]);
            }
        }
    }
}

// ---------------------------------------------------------------------------
// MFMA attention, K/V from combined KV buffer [M][512]. (validated r3-r6)
// ---------------------------------------------------------------------------
__device__ inline void stage_v_half(const u16* __restrict__ KV, u16* __restrict__ Vt,
                                    int b, int h, int HF, int tid) {
    #pragma unroll
    for (int i = 0; i < 9; ++i) {
        int c = tid + i*256;
        int k = c >> 3;            // 0..287
        int d0 = (c & 7) * 8;
        union { u32x4 v; u16 s[8]; } u;
        u.v = *(const u32x4*)(KV + ((size_t)(b*N_ + HF*288 + k))*512 + 256 + h*HD_ + d0);
        #pragma unroll
        for (int e = 0; e < 8; ++e)
            Vt[(d0 + e)*296 + k] = u.s[e];
    }
}

template<int HF>
__device__ inline void pv_half(const unsigned (&pk)[36][2], f32x4 (&cacc)[4],
                               const u16* __restrict__ Vt, int lane) {
    int s1 = (lane & 15) + ((lane & 16) << 1);
    int s2 = s1 + 16;
    bool hi = (lane & 32) != 0;
    #pragma unroll
    for (int t9 = 0; t9 < 9; ++t9) {
        const int t = HF*9 + t9;
        unsigned A01 = __shfl((int)pk[2*t  ][0], s1, 64);
        unsigned A23 = __shfl((int)pk[2*t  ][1], s1, 64);
        unsigned B01 = __shfl((int)pk[2*t+1][0], s1, 64);
        unsigned B23 = __shfl((int)pk[2*t+1][1], s1, 64);
        unsigned C01 = __shfl((int)pk[2*t  ][0], s2, 64);
        unsigned C23 = __shfl((int)pk[2*t  ][1], s2, 64);
        unsigned D01 = __shfl((int)pk[2*t+1][0], s2, 64);
        unsigned D23 = __shfl((int)pk[2*t+1][1], s2, 64);
        union { unsigned w[4]; bf16x8 v; } bu;
        bu.w[0] = hi ? B01 : A01;
        bu.w[1] = hi ? B23 : A23;
        bu.w[2] = hi ? D01 : C01;
        bu.w[3] = hi ? D23 : C23;
        int colb = 32*t - 288*HF + 8*(lane >> 4);
        #pragma unroll
        for (int dt = 0; dt < 4; ++dt) {
            bf16x8 a = *(const bf16x8*)&Vt[(16*dt + (lane & 15))*296 + colb];
            cacc[dt] = __builtin_amdgcn_mfma_f32_16x16x32_bf16(a, bu.v, cacc[dt], 0, 0, 0);
        }
    }
}

__global__ __launch_bounds__(256, 2)
void attn_mfma_kernel(const u16* __restrict__ Qbf, const u16* __restrict__ KV,
                      const float* __restrict__ mask,
                      float* __restrict__ attn_out, u16* __restrict__ ctxb) {
    __shared__ u16 Vt[64*296];
    __shared__ float Msk[576];
    int tid = threadIdx.x;
    int lane = tid & 63, wid = tid >> 6;
    int qb, bh;
    xcd_remap<9, 128>(qb, bh);
    int b = bh >> 2, h = bh & 3;
    int q0 = qb * 64;
    int g = lane >> 4;
    int qrow = q0 + wid*16 + (lane & 15);

    if (tid < 144) {
        float4 mv = *(const float4*)(mask + b*N_ + tid*4);
        *(float4*)&Msk[tid*4] = make_float4(ALPHA_*mv.x, ALPHA_*mv.y, ALPHA_*mv.z, ALPHA_*mv.w);
    }
    stage_v_half(KV, Vt, b, h, 0, tid);
    __syncthreads();

    const u16* qp = Qbf + ((size_t)(b*N_) + qrow)*INNER_ + h*HD_ + g*8;
    bf16x8 qf0 = *(const bf16x8*)qp;
    bf16x8 qf1 = *(const bf16x8*)(qp + 32);

    f32x4 acc[36];
    #pragma unroll
    for (int T = 0; T < 36; ++T) acc[T] = (f32x4){0.f, 0.f, 0.f, 0.f};

    const u16* kp = KV + ((size_t)(b*N_) + (lane & 15))*512 + h*HD_ + g*8;
    bf16x8 kb[2][2];
    kb[0][0] = *(const bf16x8*)(kp);
    kb[0][1] = *(const bf16x8*)(kp + 32);
    kb[1][0] = *(const bf16x8*)(kp + 16*512);
    kb[1][1] = *(const bf16x8*)(kp + 16*512 + 32);
    #pragma unroll
    for (int T = 0; T < 36; ++T) {
        bf16x8 n0, n1;
        if (T + 2 < 36) {
            n0 = *(const bf16x8*)(kp + (size_t)(T+2)*16*512);
            n1 = *(const bf16x8*)(kp + (size_t)(T+2)*16*512 + 32);
        }
        acc[T] = __builtin_amdgcn_mfma_f32_16x16x32_bf16(kb[T&1][0], qf0, acc[T], 0, 0, 0);
        acc[T] = __builtin_amdgcn_mfma_f32_16x16x32_bf16(kb[T&1][1], qf1, acc[T], 0, 0, 0);
        if (T + 2 < 36) { kb[T&1][0] = n0; kb[T&1][1] = n1; }
    }

    float m = -1e30f;
    #pragma unroll
    for (int T = 0; T < 36; ++T) {
        float4 mk = *(const float4*)&Msk[16*T + 4*g];
        acc[T][0] = acc[T][0]*0.125f + mk.x;
        acc[T][1] = acc[T][1]*0.125f + mk.y;
        acc[T][2] = acc[T][2]*0.125f + mk.z;
        acc[T][3] = acc[T][3]*0.125f + mk.w;
        m = fmaxf(m, fmaxf(fmaxf(acc[T][0], acc[T][1]), fmaxf(acc[T][2], acc[T][3])));
    }
    m = fmaxf(m, __shfl_xor(m, 16, 64));
    m = fmaxf(m, __shfl_xor(m, 32, 64));

    float l = 0.f;
    #pragma unroll
    for (int T = 0; T < 36; ++T) {
        acc[T][0] = expf(acc[T][0] - m);
        acc[T][1] = expf(acc[T][1] - m);
        acc[T][2] = expf(acc[T][2] - m);
        acc[T][3] = expf(acc[T][3] - m);
        l += acc[T][0] + acc[T][1] + acc[T][2] + acc[T][3];
    }
    l += __shfl_xor(l, 16, 64);
    l += __shfl_xor(l, 32, 64);
    float inv = 1.f / l;

    unsigned pk[36][2];
    float* ap = attn_out + ((size_t)bh*N_ + qrow)*N_;
    #pragma unroll
    for (int T = 0; T < 36; ++T) {
        float e0 = acc[T][0]*inv, e1 = acc[T][1]*inv;
        float e2 = acc[T][2]*inv, e3 = acc[T][3]*inv;
        f32x4 ov = {e0, e1, e2, e3};
        __builtin_nontemporal_store(ov, (f32x4*)(ap + 16*T + 4*g));
        pk[T][0] = pack2bf(e0, e1);
        pk[T][1] = pack2bf(e2, e3);
    }

    f32x4 cacc[4] = {};
    pv_half<0>(pk, cacc, Vt, lane);
    __syncthreads();
    stage_v_half(KV, Vt, b, h, 1, tid);
    __syncthreads();
    pv_half<1>(pk, cacc, Vt, lane);

    u16* cp = ctxb + ((size_t)(b*N_) + qrow)*INNER_ + h*HD_ + 4*g;
    #pragma unroll
    for (int dt = 0; dt < 4; ++dt) {
        ushort4 o;
        o.x = bfbits(cacc[dt][0]);
        o.y = bfbits(cacc[dt][1]);
        o.z = bfbits(cacc[dt][2]);
        o.w = bfbits(cacc[dt][3]);
        *(ushort4*)(cp + 16*dt) = o;
    }
}

// ---------------------------------------------------------------------------
extern "C" void kernel_launch(void* const* d_in, const int* in_sizes, int n_in,
                              void* d_out, int out_size, void* d_ws, size_t ws_size,
                              hipStream_t stream) {
    const float* query   = (const float*)d_in[0];
    const float* support = (const float*)d_in[1];
    const float* mask    = (const float*)d_in[2];
    const float* ln_q_w  = (const float*)d_in[3];
    const float* ln_q_b  = (const float*)d_in[4];
    const float* ln_s_w  = (const float*)d_in[5];
    const float* ln_s_b  = (const float*)d_in[6];
    const float* Wq      = (const float*)d_in[7];
    const float* bq      = (const float*)d_in[8];
    const float* Wk      = (const float*)d_in[9];
    const float* bk      = (const float*)d_in[10];
    const float* Wv      = (const float*)d_in[11];
    const float* bv      = (const float*)d_in[12];
    const float* Wo      = (const float*)d_in[13];
    const float* bo      = (const float*)d_in[14];
    const float* Wg      = (const float*)d_in[15];
    const float* bg      = (const float*)d_in[16];

    float* out      = (float*)d_out;
    float* attn_out = out + (size_t)M_ * C_;

    char* w = (char*)d_ws;
    u16* Aq    = (u16*)w;  w += (size_t)M_*C_*2;
    u16* As_   = (u16*)w;  w += (size_t)M_*C_*2;
    u16* Xq    = (u16*)w;  w += (size_t)M_*C_*2;
    u16* Wq_b  = (u16*)w;  w += (size_t)INNER_*C_*2;
    u16* Wkv_b = (u16*)w;  w += (size_t)2*INNER_*C_*2;
    u16* Wo_b  = (u16*)w;  w += (size_t)C_*INNER_*2;
    u16* Wg_b  = (u16*)w;  w += (size_t)C_*C_*2;
    float* bkv = (float*)w; w += 512*4;
    u16* Qbf   = (u16*)w;  w += (size_t)M_*INNER_*2;
    u16* KVbf  = (u16*)w;  w += (size_t)M_*2*INNER_*2;
    u16* ctxb  = (u16*)w;  w += (size_t)M_*INNER_*2;

    // Fused LN for both tensors; query pass also emits raw bf16 (Xq)
    ln_fused2_kernel<<<dim3(M_/4, 2), dim3(256), 0, stream>>>(
        query, support, ln_q_w, ln_q_b, ln_s_w, ln_s_b, Aq, As_, Xq);

    // All weight conversions + combined kv bias
    cvt_weights_kernel<<<dim3(1024), dim3(256), 0, stream>>>(
        Wq, Wk, Wv, Wo, Wg, bk, bv, Wq_b, Wkv_b, Wo_b, Wg_b, bkv);

    // Q + KV projections, one launch, row-band clustered
    qkv_gemm_kernel<<<dim3(6, 144), dim3(256), 0, stream>>>(
        Aq, As_, Wq_b, Wkv_b, bq, bkv, Qbf, KVbf);

    // attention
    attn_mfma_kernel<<<dim3(N_/64, B_*H_), dim3(256), 0, stream>>>(
        Qbf, KVbf, mask, attn_out, ctxb);

    // fused gate + output proj + residual
    final_fused_kernel<<<dim3(8, 144), dim3(256), 0, stream>>>(
        query, Xq, Wg_b, bg, ctxb, Wo_b, bo, out);
}